// Round 9
// baseline (863.637 us; speedup 1.0000x reference)
//
#include <hip/hip_runtime.h>
#include <cstdint>
#include <cstddef>

#define D 1024
#define BATCH 16384
#define NLAYERS 18
#define RR 32

typedef __attribute__((ext_vector_type(8))) __bf16 bf16x8;
typedef __attribute__((ext_vector_type(4))) float f32x4;
typedef __attribute__((address_space(3))) void lds_void_t;
typedef __attribute__((address_space(1))) void gmem_void_t;

union bfpack { unsigned short us[8]; int4 v; };

__device__ __forceinline__ unsigned short f2bf(float f) {
    unsigned int b = __builtin_bit_cast(unsigned int, f);
    b += 0x7fffu + ((b >> 16) & 1u);
    return (unsigned short)(b >> 16);
}
__device__ __forceinline__ float bf2f(unsigned short u) {
    return __builtin_bit_cast(float, (unsigned int)u << 16);
}

// ---------------------------------------------------------------------------
// lora_dequant: weff = (q/15*2-1)*scale + 4*(lb@la), bf16, fused.
// R8 regression fix: lbs+lat (25.6KB staging) and out_s (33.8KB) are
// phase-disjoint -> UNION them in one 33.8KB buffer => 4 blocks/CU
// (was 59KB => 2 blocks/CU, 16% occupancy, latency-bound at 48us).
// Extra barrier between fragment loads and out_s writes guards aliasing.
// ---------------------------------------------------------------------------
__global__ __launch_bounds__(256) void lora_dequant(
    const float* __restrict__ la, const float* __restrict__ lb,
    const int* __restrict__ q, const float* __restrict__ scales,
    unsigned short* __restrict__ weff) {
    __shared__ __align__(16) char lds[33792];
    unsigned short (*lbs)[40] = (unsigned short (*)[40])lds;            // [64][40]
    unsigned short (*lat)[40] = (unsigned short (*)[40])(lds + 5120);   // [256][40]
    unsigned short (*out_s)[264] = (unsigned short (*)[264])lds;        // [64][264] aliases
    const int b = blockIdx.x;                  // 18*16*4
    const int li = b >> 6;
    const int o0 = ((b >> 2) & 15) << 6;
    const int i0 = (b & 3) << 8;
    const int t = threadIdx.x;

    {   // lbs: 64x32 f32 -> bf16
        const int row = t >> 2, qt = t & 3;
        const float* src = lb + ((size_t)(li * D) + o0 + row) * RR + qt * 8;
        float4 v0 = ((const float4*)src)[0], v1 = ((const float4*)src)[1];
        bfpack u;
        u.us[0] = f2bf(v0.x); u.us[1] = f2bf(v0.y); u.us[2] = f2bf(v0.z); u.us[3] = f2bf(v0.w);
        u.us[4] = f2bf(v1.x); u.us[5] = f2bf(v1.y); u.us[6] = f2bf(v1.z); u.us[7] = f2bf(v1.w);
        *(int4*)&lbs[row][qt * 8] = u.v;
    }
    {   // lat[col][r] = bf16(la[li][r][i0+col])
        const int col = t;
#pragma unroll 8
        for (int r = 0; r < 32; ++r)
            lat[col][r] = f2bf(la[((size_t)li * RR + r) * D + i0 + col]);
    }
    __syncthreads();

    // fragment loads (regs), then barrier BEFORE aliased out_s writes
    const int wid = t >> 6, lane = t & 63;
    const int l15 = lane & 15, kgrp = lane >> 4;
    const int wrow = (wid >> 1) << 5;   // 0/32
    const int wcol = (wid & 1) << 7;    // 0/128
    bf16x8 a[2], bb[8];
#pragma unroll
    for (int f = 0; f < 2; ++f)
        a[f] = *(const bf16x8*)&lbs[wrow + (f << 4) + l15][kgrp << 3];
#pragma unroll
    for (int g = 0; g < 8; ++g)
        bb[g] = *(const bf16x8*)&lat[wcol + (g << 4) + l15][kgrp << 3];
    __syncthreads();   // all waves' LDS reads complete (lgkmcnt(0)+barrier)

    {   // MFMA + write lora tile to out_s (aliased region)
        f32x4 acc[2][8];
#pragma unroll
        for (int i = 0; i < 2; ++i)
#pragma unroll
            for (int j = 0; j < 8; ++j) acc[i][j] = 0.0f;
#pragma unroll
        for (int mi = 0; mi < 2; ++mi)
#pragma unroll
            for (int ni = 0; ni < 8; ++ni)
                acc[mi][ni] = __builtin_amdgcn_mfma_f32_16x16x32_bf16(
                    a[mi], bb[ni], acc[mi][ni], 0, 0, 0);
        // C/D: col = l15, row = kgrp*4 + r
#pragma unroll
        for (int mi = 0; mi < 2; ++mi) {
            const int row = wrow + (mi << 4) + (kgrp << 2);
#pragma unroll
            for (int ni = 0; ni < 8; ++ni) {
                const int col = wcol + (ni << 4) + l15;
#pragma unroll
                for (int r = 0; r < 4; ++r)
                    out_s[row + r][col] = f2bf(4.0f * acc[mi][ni][r]);
            }
        }
    }
    __syncthreads();

    // coalesced dequant pass
    const float c = 2.0f / 15.0f;
#pragma unroll 1
    for (int iter = 0; iter < 8; ++iter) {
        const int idx = (iter << 8) + t;
        const int row = idx >> 5, c8 = (idx & 31) << 3;
        const size_t grow = (size_t)li * D + o0 + row;
        const int col = i0 + c8;
        const float s = scales[grow * (D / 16) + (col >> 4)];
        const int* qp = q + grow * D + col;
        int4 q0 = ((const int4*)qp)[0], q1 = ((const int4*)qp)[1];
        bfpack lo;
        lo.v = *(const int4*)&out_s[row][c8];
        int qa[8] = {q0.x, q0.y, q0.z, q0.w, q1.x, q1.y, q1.z, q1.w};
        bfpack u;
#pragma unroll
        for (int j = 0; j < 8; ++j)
            u.us[j] = f2bf(((float)qa[j] * c - 1.0f) * s + bf2f(lo.us[j]));
        *(int4*)(weff + grow * D + col) = u.v;
    }
}

// xb = bf16(x)
__global__ __launch_bounds__(256) void init_xb(const float* __restrict__ x,
                                               unsigned short* __restrict__ xb) {
    const size_t i = (size_t)blockIdx.x * 256 + threadIdx.x;
    float4 v = ((const float4*)x)[i];
    ushort4 u;
    u.x = f2bf(v.x); u.y = f2bf(v.y); u.z = f2bf(v.z); u.w = f2bf(v.w);
    ((ushort4*)xb)[i] = u;
}

#define SBAR() do { asm volatile("" ::: "memory"); __builtin_amdgcn_s_barrier(); asm volatile("" ::: "memory"); } while (0)

// ---------------------------------------------------------------------------
// gemm256 (v4): 256x256 tile, 8 waves, 4-slot ring, depth-3 vmcnt(8).
// [R3/R7-verified ~37us avg @ K=1024]. 128KB LDS -> 1 block/CU.
// ---------------------------------------------------------------------------
__global__ __launch_bounds__(512, 2) void gemm256(
    const unsigned short* __restrict__ xb, const unsigned short* __restrict__ w,
    const float* __restrict__ bias,
    unsigned short* __restrict__ outb, int mode) {
    __shared__ __align__(16) char smem[131072];
    const int tid = threadIdx.x;
    const int wid = tid >> 6, lane = tid & 63;
    const int bid = blockIdx.x + (blockIdx.y << 2);
    const int xcd = bid & 7, slot = bid >> 3;
    const int m0 = ((xcd << 3) + (slot >> 2)) << 8;
    const int n0 = (slot & 3) << 8;
    const int l15 = lane & 15, kgrp = lane >> 4;
    const int wrow = (wid >> 2) << 7;
    const int wcol = (wid & 3) << 6;

    f32x4 acc[8][4];
#pragma unroll
    for (int i = 0; i < 8; ++i)
#pragma unroll
        for (int j = 0; j < 4; ++j) acc[i][j] = 0.0f;

#define STAGE_HALF(hs, i_)                                                     \
    do {                                                                       \
        const int k0_ = (hs) << 5;                                             \
        char* sA_ = smem + ((hs) & 3) * 32768;                                 \
        const int off_ = (i_) * 8192 + (tid << 4);                             \
        const int r_ = off_ >> 6;                                              \
        const int j_ = ((off_ >> 4) & 3) ^ ((r_ >> 1) & 3);                    \
        const unsigned short* ga_ = xb + (size_t)(m0 + r_) * D + k0_ + (j_ << 3); \
        const unsigned short* gb_ = w + (size_t)(n0 + r_) * D + k0_ + (j_ << 3);  \
        char* lA_ = sA_ + (i_) * 8192 + (wid << 10);                           \
        __builtin_amdgcn_global_load_lds((const gmem_void_t*)ga_, (lds_void_t*)lA_, 16, 0, 0);          \
        __builtin_amdgcn_global_load_lds((const gmem_void_t*)gb_, (lds_void_t*)(lA_ + 16384), 16, 0, 0); \
    } while (0)

    STAGE_HALF(0, 0); STAGE_HALF(0, 1);
    STAGE_HALF(1, 0); STAGE_HALF(1, 1);
    STAGE_HALF(2, 0); STAGE_HALF(2, 1);
    asm volatile("s_waitcnt vmcnt(8)" ::: "memory");
    SBAR();

    for (int h = 0; h < 32; ++h) {
        const char* sA = smem + (h & 3) * 32768;
        const char* sB = sA + 16384;
        bf16x8 a[8], b[4];
#pragma unroll
        for (int f = 0; f < 4; ++f) {
            const int r = wrow + (f << 4) + l15;
            a[f] = *(const bf16x8*)(sA + (r << 6) + ((kgrp ^ ((r >> 1) & 3)) << 4));
        }
#pragma unroll
        for (int g = 0; g < 4; ++g) {
            const int r = wcol + (g << 4) + l15;
            b[g] = *(const bf16x8*)(sB + (r << 6) + ((kgrp ^ ((r >> 1) & 3)) << 4));
        }
        if (h < 29) STAGE_HALF(h + 3, 0);
        SBAR();
        asm volatile("s_waitcnt lgkmcnt(0)" ::: "memory");
        __builtin_amdgcn_s_setprio(1);
#pragma unroll
        for (int mi = 0; mi < 4; ++mi)
#pragma unroll
            for (int ni = 0; ni < 4; ++ni)
                acc[mi][ni] = __builtin_amdgcn_mfma_f32_16x16x32_bf16(
                    a[mi], b[ni], acc[mi][ni], 0, 0, 0);
        __builtin_amdgcn_s_setprio(0);
        SBAR();
#pragma unroll
        for (int f = 4; f < 8; ++f) {
            const int r = wrow + (f << 4) + l15;
            a[f] = *(const bf16x8*)(sA + (r << 6) + ((kgrp ^ ((r >> 1) & 3)) << 4));
        }
        if (h < 29) {
            STAGE_HALF(h + 3, 1);
            asm volatile("s_waitcnt vmcnt(8)" ::: "memory");
        } else if (h == 29) {
            asm volatile("s_waitcnt vmcnt(4)" ::: "memory");
        } else if (h == 30) {
            asm volatile("s_waitcnt vmcnt(0)" ::: "memory");
        }
        SBAR();
        asm volatile("s_waitcnt lgkmcnt(0)" ::: "memory");
        __builtin_amdgcn_s_setprio(1);
#pragma unroll
        for (int mi = 4; mi < 8; ++mi)
#pragma unroll
            for (int ni = 0; ni < 4; ++ni)
                acc[mi][ni] = __builtin_amdgcn_mfma_f32_16x16x32_bf16(
                    a[mi], b[ni], acc[mi][ni], 0, 0, 0);
        __builtin_amdgcn_s_setprio(0);
        SBAR();
    }

    const int crow = kgrp << 2;
    float bv[4];
#pragma unroll
    for (int ni = 0; ni < 4; ++ni) bv[ni] = bias[n0 + wcol + (ni << 4) + l15];
#pragma unroll
    for (int mi = 0; mi < 8; ++mi) {
        const int rbase = m0 + wrow + (mi << 4) + crow;
#pragma unroll
        for (int ni = 0; ni < 4; ++ni) {
            const int col = n0 + wcol + (ni << 4) + l15;
#pragma unroll
            for (int r = 0; r < 4; ++r) {
                float v = acc[mi][ni][r] + bv[ni];
                if (mode == 0) v = v > 0.0f ? v : 0.0f;
                outb[(size_t)(rbase + r) * D + col] = f2bf(v);
            }
        }
    }
}

// ---------------------------------------------------------------------------
// gemm256_v2: 256x128 tile, 8 waves (2Mx4N), 3-slot ring (72KB LDS),
// depth-2 counted vmcnt(3), grid 512 => 2 blocks/CU (cross-block barrier
// overlap, the m114 mechanism v4 lacks at 1 block/CU). One phase per
// half-step: {10 ds_read, 3 stage loads, vmcnt, SBAR, lgkm0, 16 MFMA, SBAR}.
// Slot h confirmed landed by phase h-1's vmcnt+SBAR before phase h reads it.
// ---------------------------------------------------------------------------
__global__ __launch_bounds__(512, 4) void gemm256_v2(
    const unsigned short* __restrict__ xb, const unsigned short* __restrict__ w,
    const float* __restrict__ bias,
    unsigned short* __restrict__ outb, int mode) {
    __shared__ __align__(16) char smem[73728];   // 3 x (A 16K + B 8K)
    const int tid = threadIdx.x;
    const int wid = tid >> 6, lane = tid & 63;
    const int bid = blockIdx.x + (blockIdx.y << 3);
    const int xcd = bid & 7, slot = bid >> 3;        // slot 0..63
    const int m0 = ((xcd << 3) + (slot >> 3)) << 8;  // 64 m-tiles
    const int n0 = (slot & 7) << 7;                  // 8 n-tiles
    const int l15 = lane & 15, kgrp = lane >> 4;
    const int wrow = (wid >> 2) << 7;   // 0/128
    const int wcol = (wid & 3) << 5;    // 0..96

    f32x4 acc[8][2];
#pragma unroll
    for (int i = 0; i < 8; ++i)
#pragma unroll
        for (int j = 0; j < 2; ++j) acc[i][j] = 0.0f;

#define STAGE2(hs)                                                             \
    do {                                                                       \
        const int k0_ = (hs) << 5;                                             \
        char* b_ = smem + ((hs) % 3) * 24576;                                  \
        _Pragma("unroll")                                                      \
        for (int i_ = 0; i_ < 2; ++i_) {                                       \
            const int off_ = i_ * 8192 + (tid << 4);                           \
            const int r_ = off_ >> 6;                                          \
            const int j_ = ((off_ >> 4) & 3) ^ ((r_ >> 1) & 3);                \
            const unsigned short* ga_ = xb + (size_t)(m0 + r_) * D + k0_ + (j_ << 3); \
            __builtin_amdgcn_global_load_lds((const gmem_void_t*)ga_,          \
                (lds_void_t*)(b_ + i_ * 8192 + (wid << 10)), 16, 0, 0);        \
        }                                                                      \
        {                                                                      \
            const int off_ = tid << 4;                                         \
            const int r_ = off_ >> 6;                                          \
            const int j_ = ((off_ >> 4) & 3) ^ ((r_ >> 1) & 3);                \
            const unsigned short* gb_ = w + (size_t)(n0 + r_) * D + k0_ + (j_ << 3);  \
            __builtin_amdgcn_global_load_lds((const gmem_void_t*)gb_,          \
                (lds_void_t*)(b_ + 16384 + (wid << 10)), 16, 0, 0);            \
        }                                                                      \
    } while (0)

    STAGE2(0); STAGE2(1);
    asm volatile("s_waitcnt vmcnt(3)" ::: "memory");   // S0 landed
    SBAR();

    for (int h = 0; h < 32; ++h) {
        const char* sA = smem + (h % 3) * 24576;
        const char* sB = sA + 16384;
        bf16x8 a[8], b[2];
#pragma unroll
        for (int f = 0; f < 8; ++f) {
            const int r = wrow + (f << 4) + l15;
            a[f] = *(const bf16x8*)(sA + (r << 6) + ((kgrp ^ ((r >> 1) & 3)) << 4));
        }
#pragma unroll
        for (int g = 0; g < 2; ++g) {
            const int r = wcol + (g << 4) + l15;
            b[g] = *(const bf16x8*)(sB + (r << 6) + ((kgrp ^ ((r >> 1) & 3)) << 4));
        }
        if (h < 30) {
            STAGE2(h + 2);
            asm volatile("s_waitcnt vmcnt(3)" ::: "memory");  // S_{h+1} landed
        } else if (h == 30) {
            asm volatile("s_waitcnt vmcnt(0)" ::: "memory");  // S31 landed
        }
        SBAR();
        asm volatile("s_waitcnt lgkmcnt(0)" ::: "memory");
        __builtin_amdgcn_s_setprio(1);
#pragma unroll
        for (int mi = 0; mi < 8; ++mi)
#pragma unroll
            for (int ni = 0; ni < 2; ++ni)
                acc[mi][ni] = __builtin_amdgcn_mfma_f32_16x16x32_bf16(
                    a[mi], b[ni], acc[mi][ni], 0, 0, 0);
        __builtin_amdgcn_s_setprio(0);
        SBAR();
    }

    const int crow = kgrp << 2;
    float bv[2];
#pragma unroll
    for (int ni = 0; ni < 2; ++ni) bv[ni] = bias[n0 + wcol + (ni << 4) + l15];
#pragma unroll
    for (int mi = 0; mi < 8; ++mi) {
        const int rbase = m0 + wrow + (mi << 4) + crow;
#pragma unroll
        for (int ni = 0; ni < 2; ++ni) {
            const int col = n0 + wcol + (ni << 4) + l15;
#pragma unroll
            for (int r = 0; r < 4; ++r) {
                float v = acc[mi][ni][r] + bv[ni];
                if (mode == 0) v = v > 0.0f ? v : 0.0f;
                outb[(size_t)(rbase + r) * D + col] = f2bf(v);
            }
        }
    }
}

// hb = bf16(LN(hb + vb)) in place
__global__ __launch_bounds__(256) void resid_ln_b(
    unsigned short* __restrict__ hb, const unsigned short* __restrict__ vb,
    const float* __restrict__ gamma, const float* __restrict__ beta) {
    const int row = blockIdx.x;
    const int t = threadIdx.x;
    unsigned short* hr = hb + (size_t)row * D;
    ushort4 hv = ((const ushort4*)hr)[t];
    ushort4 vv = ((const ushort4*)(vb + (size_t)row * D))[t];
    float4 v;
    v.x = bf2f(hv.x) + bf2f(vv.x); v.y = bf2f(hv.y) + bf2f(vv.y);
    v.z = bf2f(hv.z) + bf2f(vv.z); v.w = bf2f(hv.w) + bf2f(vv.w);
    float s = v.x + v.y + v.z + v.w;
    float s2 = v.x * v.x + v.y * v.y + v.z * v.z + v.w * v.w;
#pragma unroll
    for (int off = 32; off > 0; off >>= 1) {
        s += __shfl_down(s, off);
        s2 += __shfl_down(s2, off);
    }
    __shared__ float red[8];
    const int wid = t >> 6, lane = t & 63;
    if (lane == 0) { red[wid] = s; red[wid + 4] = s2; }
    __syncthreads();
    s = red[0] + red[1] + red[2] + red[3];
    s2 = red[4] + red[5] + red[6] + red[7];
    const float mu = s * (1.0f / D);
    const float var = s2 * (1.0f / D) - mu * mu;
    const float rs = rsqrtf(var + 1e-5f);
    float4 g = ((const float4*)gamma)[t];
    float4 b = ((const float4*)beta)[t];
    ushort4 u;
    u.x = f2bf((v.x - mu) * rs * g.x + b.x);
    u.y = f2bf((v.y - mu) * rs * g.y + b.y);
    u.z = f2bf((v.z - mu) * rs * g.z + b.z);
    u.w = f2bf((v.w - mu) * rs * g.w + b.w);
    ((ushort4*)hr)[t] = u;
}

// out = h + v  (final block)
__global__ __launch_bounds__(256) void final_add(
    const unsigned short* __restrict__ hb, const unsigned short* __restrict__ vb,
    float* __restrict__ out) {
    const size_t i = (size_t)blockIdx.x * 256 + threadIdx.x;
    ushort4 hv = ((const ushort4*)hb)[i];
    ushort4 vv = ((const ushort4*)vb)[i];
    float4 o;
    o.x = bf2f(hv.x) + bf2f(vv.x); o.y = bf2f(hv.y) + bf2f(vv.y);
    o.z = bf2f(hv.z) + bf2f(vv.z); o.w = bf2f(hv.w) + bf2f(vv.w);
    ((float4*)out)[i] = o;
}

static void run_gemm(const unsigned short* in, const unsigned short* wl,
                     const float* bias, unsigned short* outb, int mode,
                     int li, hipStream_t stream) {
    if (li & 1) {
        dim3 g(8, 64);
        gemm256_v2<<<g, 512, 0, stream>>>(in, wl, bias, outb, mode);
    } else {
        dim3 g(4, 64);
        gemm256<<<g, 512, 0, stream>>>(in, wl, bias, outb, mode);
    }
}

extern "C" void kernel_launch(void* const* d_in, const int* in_sizes, int n_in,
                              void* d_out, int out_size, void* d_ws, size_t ws_size,
                              hipStream_t stream) {
    const float* x      = (const float*)d_in[0];
    const int*   q      = (const int*)d_in[1];
    const float* scales = (const float*)d_in[2];
    const float* biases = (const float*)d_in[3];
    const float* la     = (const float*)d_in[4];
    const float* lb     = (const float*)d_in[5];
    const float* lng    = (const float*)d_in[6];
    const float* lnb    = (const float*)d_in[7];
    float* out = (float*)d_out;

    char* p = (char*)d_ws;
    unsigned short* weff = (unsigned short*)p; p += (size_t)NLAYERS * D * D * 2;
    unsigned short* xbA  = (unsigned short*)p; p += (size_t)BATCH * D * 2;
    unsigned short* xbB  = (unsigned short*)p; p += (size_t)BATCH * D * 2;
    unsigned short* xbC  = (unsigned short*)p;

    lora_dequant<<<NLAYERS * 16 * 4, 256, 0, stream>>>(la, lb, q, scales, weff);
    init_xb<<<BATCH * D / 4 / 256, 256, 0, stream>>>(x, xbA);

    for (int blk = 0; blk < 6; ++blk) {
        const int li = 3 * blk;
        run_gemm(xbA, weff + (size_t)li * D * D, biases + (size_t)li * D, xbB, 0, li, stream);
        run_gemm(xbB, weff + (size_t)(li + 1) * D * D, biases + (size_t)(li + 1) * D, xbC, 0, li + 1, stream);
        run_gemm(xbC, weff + (size_t)(li + 2) * D * D, biases + (size_t)(li + 2) * D, xbB, 1, li + 2, stream);
        if (blk < 5)
            resid_ln_b<<<BATCH, 256, 0, stream>>>(xbA, xbB,
                                                  lng + (size_t)blk * D, lnb + (size_t)blk * D);
        else
            final_add<<<BATCH * D / 4 / 256, 256, 0, stream>>>(xbA, xbB, out);
    }
}